// Round 1
// baseline (1006.530 us; speedup 1.0000x reference)
//
#include <hip/hip_runtime.h>
#include <math.h>

#define DTC 0.1f
#define TTC 10.0f   // t = DT/EPS

// ================= precompute kernels (4 layers of 256x256 mats) ============

// E = DT^2 * W * W^T
__global__ void k_compE(const float* __restrict__ W0, const float* __restrict__ W1,
                        const float* __restrict__ W2, const float* __restrict__ W3,
                        float* __restrict__ E) {
  const float* Ws[4] = {W0, W1, W2, W3};
  const float* W = Ws[blockIdx.z];
  float* Eo = E + (size_t)blockIdx.z * 65536;
  __shared__ float As[16][17], Bs[16][17];
  const int tx = threadIdx.x, ty = threadIdx.y;
  const int i = blockIdx.y * 16 + ty;
  const int j = blockIdx.x * 16 + tx;
  float acc = 0.f;
  for (int k0 = 0; k0 < 256; k0 += 16) {
    As[ty][tx] = W[i * 256 + k0 + tx];
    Bs[ty][tx] = W[(blockIdx.x * 16 + ty) * 256 + k0 + tx];
    __syncthreads();
#pragma unroll
    for (int k = 0; k < 16; ++k) acc += As[ty][k] * Bs[tx][k];
    __syncthreads();
  }
  Eo[i * 256 + j] = 0.01f * acc;
}

// Pa = I - E
__global__ void k_initP(const float* __restrict__ E, float* __restrict__ Pa) {
  const int idx = blockIdx.x * 256 + threadIdx.x;  // 0 .. 4*65536-1
  const int ij = idx & 65535;
  const int i = ij >> 8, j = ij & 255;
  Pa[idx] = (i == j ? 1.f : 0.f) - E[idx];
}

// Pd = I - E @ Ps   (Neumann iteration)
__global__ void k_neumann(const float* __restrict__ E, const float* __restrict__ Ps,
                          float* __restrict__ Pd) {
  const int l = blockIdx.z;
  const float* El = E + (size_t)l * 65536;
  const float* S = Ps + (size_t)l * 65536;
  float* D = Pd + (size_t)l * 65536;
  __shared__ float As[16][17], Bs[16][17];
  const int tx = threadIdx.x, ty = threadIdx.y;
  const int i = blockIdx.y * 16 + ty;
  const int j = blockIdx.x * 16 + tx;
  float acc = 0.f;
  for (int k0 = 0; k0 < 256; k0 += 16) {
    As[ty][tx] = El[i * 256 + k0 + tx];
    Bs[ty][tx] = S[(k0 + ty) * 256 + j];
    __syncthreads();
#pragma unroll
    for (int k = 0; k < 16; ++k) acc += As[ty][k] * Bs[k][tx];
    __syncthreads();
  }
  D[i * 256 + j] = (i == j ? 1.f : 0.f) - acc;
}

// Pm = -P ; Q = DT * W^T @ P ; Rm = DT*(1-t)*W = -0.9*W
__global__ void k_finish(const float* __restrict__ W0, const float* __restrict__ W1,
                         const float* __restrict__ W2, const float* __restrict__ W3,
                         const float* __restrict__ Pa, float* __restrict__ Pm,
                         float* __restrict__ Q, float* __restrict__ Rm) {
  const float* Ws[4] = {W0, W1, W2, W3};
  const int l = blockIdx.z;
  const float* W = Ws[l];
  const float* P = Pa + (size_t)l * 65536;
  __shared__ float As[16][17], Bs[16][17];
  const int tx = threadIdx.x, ty = threadIdx.y;
  const int i = blockIdx.y * 16 + ty;   // k-index of Q
  const int j = blockIdx.x * 16 + tx;   // n-index of Q
  float acc = 0.f;
  for (int m0 = 0; m0 < 256; m0 += 16) {
    As[ty][tx] = W[(m0 + ty) * 256 + blockIdx.y * 16 + tx];  // W[m][i-range]
    Bs[ty][tx] = P[(m0 + ty) * 256 + j];                     // P[m][j]
    __syncthreads();
#pragma unroll
    for (int m = 0; m < 16; ++m) acc += As[m][ty] * Bs[m][tx];
    __syncthreads();
  }
  const size_t o = (size_t)l * 65536 + i * 256 + j;
  Q[o]  = DTC * acc;
  Pm[o] = -P[i * 256 + j];
  Rm[o] = -0.9f * W[i * 256 + j];
}

// ================= main batch kernels ========================================

// r1 = u + DT*b ; r2 = (v + t*tanh(u))/(1+t)   (in place)
__global__ __launch_bounds__(256) void k_elem(float* __restrict__ U, float* __restrict__ V,
                                              const float* __restrict__ b) {
  const int i = blockIdx.x * 256 + threadIdx.x;  // float4 index
  float4 u = ((const float4*)U)[i];
  float4 v = ((const float4*)V)[i];
  const float4 bb = ((const float4*)b)[i & 63];
  const float inv = 1.f / (1.f + TTC);
  float4 r1, r2;
  r1.x = u.x + DTC * bb.x; r1.y = u.y + DTC * bb.y;
  r1.z = u.z + DTC * bb.z; r1.w = u.w + DTC * bb.w;
  r2.x = (v.x + TTC * tanhf(u.x)) * inv;
  r2.y = (v.y + TTC * tanhf(u.y)) * inv;
  r2.z = (v.z + TTC * tanhf(u.z)) * inv;
  r2.w = (v.w + TTC * tanhf(u.w)) * inv;
  ((float4*)U)[i] = r1;
  ((float4*)V)[i] = r2;
}

// C[M x 256] = A0 @ B0 (+ A1 @ B1 if nkt==32), with epilogues.
// TRANSB: B stored [n][k] (ldb=256) instead of [k][n].
// EPI 0: C = acc              (u_next = r1@Pm + r2@Q)
// EPI 1: C = acc + bias; V = tanh(C)      (input layer)
// EPI 2: C = acc - C          (v_next = u_next@Rm - r2, in-place on V)
template <int TRANSB, int EPI>
__global__ __launch_bounds__(256) void k_gemm(
    const float* __restrict__ A0, const float* __restrict__ B0,
    const float* __restrict__ A1, const float* __restrict__ B1,
    float* __restrict__ C, const float* __restrict__ bias,
    float* __restrict__ V, int nkt) {
  __shared__ float As[16][128];
  __shared__ float Bs[16][64];
  const int tid = threadIdx.x;
  const int m0 = blockIdx.y * 128;
  const int n0 = blockIdx.x * 64;
  float acc[8][4];
#pragma unroll
  for (int r = 0; r < 8; ++r)
#pragma unroll
    for (int c = 0; c < 4; ++c) acc[r][c] = 0.f;

  const int c4 = tid & 3;      // k-float4 within 16
  const int arow = tid >> 2;   // 0..63
  const int tcol = tid & 15;
  const int trow = tid >> 4;

  for (int kt = 0; kt < nkt; ++kt) {
    const float* A = (kt < 16) ? A0 : A1;
    const float* Bm = (kt < 16) ? B0 : B1;
    const int k0 = (kt & 15) * 16;
    // stage A tile: 128 rows x 16 k
    {
      float4 a = *(const float4*)&A[(size_t)(m0 + arow) * 256 + k0 + c4 * 4];
      As[c4 * 4 + 0][arow] = a.x;
      As[c4 * 4 + 1][arow] = a.y;
      As[c4 * 4 + 2][arow] = a.z;
      As[c4 * 4 + 3][arow] = a.w;
      float4 a2 = *(const float4*)&A[(size_t)(m0 + arow + 64) * 256 + k0 + c4 * 4];
      As[c4 * 4 + 0][arow + 64] = a2.x;
      As[c4 * 4 + 1][arow + 64] = a2.y;
      As[c4 * 4 + 2][arow + 64] = a2.z;
      As[c4 * 4 + 3][arow + 64] = a2.w;
    }
    // stage B tile: 16 k x 64 n
    if (TRANSB == 0) {
      float4 bv = *(const float4*)&Bm[(size_t)(k0 + trow) * 256 + n0 + tcol * 4];
      *(float4*)&Bs[trow][tcol * 4] = bv;
    } else {
      const int nrow = tid >> 2;  // 0..63
      float4 bv = *(const float4*)&Bm[(size_t)(n0 + nrow) * 256 + k0 + c4 * 4];
      Bs[c4 * 4 + 0][nrow] = bv.x;
      Bs[c4 * 4 + 1][nrow] = bv.y;
      Bs[c4 * 4 + 2][nrow] = bv.z;
      Bs[c4 * 4 + 3][nrow] = bv.w;
    }
    __syncthreads();
#pragma unroll
    for (int k = 0; k < 16; ++k) {
      const float4 b4 = *(const float4*)&Bs[k][tcol * 4];
      const float4 a0v = *(const float4*)&As[k][trow * 8];
      const float4 a1v = *(const float4*)&As[k][trow * 8 + 4];
      const float av[8] = {a0v.x, a0v.y, a0v.z, a0v.w, a1v.x, a1v.y, a1v.z, a1v.w};
      const float bv[4] = {b4.x, b4.y, b4.z, b4.w};
#pragma unroll
      for (int r = 0; r < 8; ++r)
#pragma unroll
        for (int c = 0; c < 4; ++c) acc[r][c] += av[r] * bv[c];
    }
    __syncthreads();
  }
  // epilogue
#pragma unroll
  for (int r = 0; r < 8; ++r) {
    const int row = m0 + trow * 8 + r;
    float* Cp = &C[(size_t)row * 256 + n0 + tcol * 4];
    float4 v;
    v.x = acc[r][0]; v.y = acc[r][1]; v.z = acc[r][2]; v.w = acc[r][3];
    if (EPI == 1) {
      const float4 bb = *(const float4*)&bias[n0 + tcol * 4];
      v.x += bb.x; v.y += bb.y; v.z += bb.z; v.w += bb.w;
      *(float4*)Cp = v;
      float4 tv;
      tv.x = tanhf(v.x); tv.y = tanhf(v.y); tv.z = tanhf(v.z); tv.w = tanhf(v.w);
      *(float4*)&V[(size_t)row * 256 + n0 + tcol * 4] = tv;
    } else if (EPI == 2) {
      const float4 old = *(const float4*)Cp;
      v.x -= old.x; v.y -= old.y; v.z -= old.z; v.w -= old.w;
      *(float4*)Cp = v;
    } else {
      *(float4*)Cp = v;
    }
  }
}

// logits = Z @ Wo^T + bo ; softmax over 10 classes. One wave per row.
__global__ __launch_bounds__(256) void k_out(const float* __restrict__ Z,
                                             const float* __restrict__ Wo,
                                             const float* __restrict__ bo,
                                             float* __restrict__ out) {
  const int wave = threadIdx.x >> 6;
  const int lane = threadIdx.x & 63;
  const int row = blockIdx.x * 4 + wave;
  const float4 z4 = *(const float4*)&Z[(size_t)row * 256 + lane * 4];
  float logit[10];
#pragma unroll
  for (int c = 0; c < 10; ++c) {
    const float4 w = *(const float4*)&Wo[c * 256 + lane * 4];
    float p = z4.x * w.x + z4.y * w.y + z4.z * w.z + z4.w * w.w;
#pragma unroll
    for (int off = 32; off; off >>= 1) p += __shfl_xor(p, off, 64);
    logit[c] = p + bo[c];
  }
  float m = logit[0];
#pragma unroll
  for (int c = 1; c < 10; ++c) m = fmaxf(m, logit[c]);
  float e[10];
  float s = 0.f;
#pragma unroll
  for (int c = 0; c < 10; ++c) { e[c] = expf(logit[c] - m); s += e[c]; }
  const float inv = 1.f / s;
  if (lane < 10) out[(size_t)row * 10 + lane] = e[lane] * inv;
}

// ================= launcher ==================================================

extern "C" void kernel_launch(void* const* d_in, const int* in_sizes, int n_in,
                              void* d_out, int out_size, void* d_ws, size_t ws_size,
                              hipStream_t stream) {
  const float* x  = (const float*)d_in[0];
  const float* Wi = (const float*)d_in[1];
  const float* bi = (const float*)d_in[2];
  const float* W[4] = {(const float*)d_in[3], (const float*)d_in[5],
                       (const float*)d_in[7], (const float*)d_in[9]};
  const float* b[4] = {(const float*)d_in[4], (const float*)d_in[6],
                       (const float*)d_in[8], (const float*)d_in[10]};
  const float* Wo = (const float*)d_in[11];
  const float* bo = (const float*)d_in[12];
  float* out = (float*)d_out;
  float* ws = (float*)d_ws;

  const int Bsz = in_sizes[0] / 256;  // 32768

  float* A0 = ws;
  float* A1 = ws + 8388608;
  float* Vb = ws + 16777216;
  float* Pm = ws + 25165824;
  float* Q  = ws + 25427968;
  float* Rm = ws + 25690112;
  float* E  = ws + 25952256;
  float* Pa = ws + 26214400;
  float* Pb = ws + 26476544;

  const dim3 blk16(16, 16);
  const dim3 grd16(16, 16, 4);
  k_compE<<<grd16, blk16, 0, stream>>>(W[0], W[1], W[2], W[3], E);
  k_initP<<<(4 * 65536) / 256, 256, 0, stream>>>(E, Pa);
  k_neumann<<<grd16, blk16, 0, stream>>>(E, Pa, Pb);
  k_neumann<<<grd16, blk16, 0, stream>>>(E, Pb, Pa);
  k_neumann<<<grd16, blk16, 0, stream>>>(E, Pa, Pb);
  k_neumann<<<grd16, blk16, 0, stream>>>(E, Pb, Pa);
  k_finish<<<grd16, blk16, 0, stream>>>(W[0], W[1], W[2], W[3], Pa, Pm, Q, Rm);

  const dim3 gg(4, Bsz / 128);  // N/64 x M/128
  // input layer: A0 = x@Wi^T + bi ; Vb = tanh(A0)
  k_gemm<1, 1><<<gg, 256, 0, stream>>>(x, Wi, nullptr, nullptr, A0, bi, Vb, 16);

  float* uin = A0;
  float* uout = A1;
  for (int l = 0; l < 4; ++l) {
    k_elem<<<Bsz / 4, 256, 0, stream>>>(uin, Vb, b[l]);
    // u_next = r1@Pm + r2@Q   (K=512)
    k_gemm<0, 0><<<gg, 256, 0, stream>>>(uin, Pm + l * 65536, Vb, Q + l * 65536,
                                         uout, nullptr, nullptr, 32);
    if (l < 3) {
      // v_next = u_next@Rm - r2   (in place on Vb)
      k_gemm<0, 2><<<gg, 256, 0, stream>>>(uout, Rm + l * 65536, nullptr, nullptr,
                                           Vb, nullptr, nullptr, 16);
    }
    float* t = uin; uin = uout; uout = t;
  }
  // uin holds z = u_out of layer 4
  k_out<<<Bsz / 4, 256, 0, stream>>>(uin, Wo, bo, out);
}

// Round 2
// 346.992 us; speedup vs baseline: 2.9007x; 2.9007x over previous
//
#include <hip/hip_runtime.h>
#include <math.h>

#define DTC 0.1f

typedef _Float16 half8 __attribute__((ext_vector_type(8)));
typedef _Float16 half4v __attribute__((ext_vector_type(4)));
typedef float f32x4 __attribute__((ext_vector_type(4)));

// ================= precompute kernels (fp32, tiny) ===========================

// E = DT^2 * W * W^T
__global__ void k_compE(const float* __restrict__ W0, const float* __restrict__ W1,
                        const float* __restrict__ W2, const float* __restrict__ W3,
                        float* __restrict__ E) {
  const float* Ws[4] = {W0, W1, W2, W3};
  const float* W = Ws[blockIdx.z];
  float* Eo = E + (size_t)blockIdx.z * 65536;
  __shared__ float As[16][17], Bs[16][17];
  const int tx = threadIdx.x, ty = threadIdx.y;
  const int i = blockIdx.y * 16 + ty;
  const int j = blockIdx.x * 16 + tx;
  float acc = 0.f;
  for (int k0 = 0; k0 < 256; k0 += 16) {
    As[ty][tx] = W[i * 256 + k0 + tx];
    Bs[ty][tx] = W[(blockIdx.x * 16 + ty) * 256 + k0 + tx];
    __syncthreads();
#pragma unroll
    for (int k = 0; k < 16; ++k) acc += As[ty][k] * Bs[tx][k];
    __syncthreads();
  }
  Eo[i * 256 + j] = 0.01f * acc;
}

// Pa = I - E
__global__ void k_initP(const float* __restrict__ E, float* __restrict__ Pa) {
  const int idx = blockIdx.x * 256 + threadIdx.x;
  const int ij = idx & 65535;
  const int i = ij >> 8, j = ij & 255;
  Pa[idx] = (i == j ? 1.f : 0.f) - E[idx];
}

// Pd = I - E @ Ps   (Neumann iteration)
__global__ void k_neumann(const float* __restrict__ E, const float* __restrict__ Ps,
                          float* __restrict__ Pd) {
  const int l = blockIdx.z;
  const float* El = E + (size_t)l * 65536;
  const float* S = Ps + (size_t)l * 65536;
  float* D = Pd + (size_t)l * 65536;
  __shared__ float As[16][17], Bs[16][17];
  const int tx = threadIdx.x, ty = threadIdx.y;
  const int i = blockIdx.y * 16 + ty;
  const int j = blockIdx.x * 16 + tx;
  float acc = 0.f;
  for (int k0 = 0; k0 < 256; k0 += 16) {
    As[ty][tx] = El[i * 256 + k0 + tx];
    Bs[ty][tx] = S[(k0 + ty) * 256 + j];
    __syncthreads();
#pragma unroll
    for (int k = 0; k < 16; ++k) acc += As[ty][k] * Bs[k][tx];
    __syncthreads();
  }
  D[i * 256 + j] = (i == j ? 1.f : 0.f) - acc;
}

// PQh[l][n][0:256]   = -P[k][n]           (fp16, n-major, K=512 rows)
// PQh[l][n][256:512] = DT*(W^T P)[k][n]
// RmTh[l][n][k]      = -0.9*W[k][n]
__global__ void k_finish(const float* __restrict__ W0, const float* __restrict__ W1,
                         const float* __restrict__ W2, const float* __restrict__ W3,
                         const float* __restrict__ Pmat, _Float16* __restrict__ PQh,
                         _Float16* __restrict__ RmTh) {
  const float* Ws[4] = {W0, W1, W2, W3};
  const int l = blockIdx.z;
  const float* W = Ws[l];
  const float* P = Pmat + (size_t)l * 65536;
  __shared__ float As[16][17], Bs[16][17];
  const int tx = threadIdx.x, ty = threadIdx.y;
  const int i = blockIdx.y * 16 + ty;   // k-index
  const int j = blockIdx.x * 16 + tx;   // n-index
  float acc = 0.f;
  for (int m0 = 0; m0 < 256; m0 += 16) {
    As[ty][tx] = W[(m0 + ty) * 256 + blockIdx.y * 16 + tx];  // W[m][i-range]
    Bs[ty][tx] = P[(m0 + ty) * 256 + j];                     // P[m][j]
    __syncthreads();
#pragma unroll
    for (int m = 0; m < 16; ++m) acc += As[m][ty] * Bs[m][tx];
    __syncthreads();
  }
  PQh[(size_t)l * 131072 + j * 512 + i]       = (_Float16)(-P[i * 256 + j]);
  PQh[(size_t)l * 131072 + j * 512 + 256 + i] = (_Float16)(DTC * acc);
  RmTh[(size_t)l * 65536 + j * 256 + i]       = (_Float16)(-0.9f * W[i * 256 + j]);
}

// fp32 -> fp16 cast, 8 elems/thread
__global__ __launch_bounds__(256) void k_cast(const float* __restrict__ in,
                                              _Float16* __restrict__ out) {
  const int i = blockIdx.x * 256 + threadIdx.x;
  const float4 a = ((const float4*)in)[i * 2];
  const float4 b = ((const float4*)in)[i * 2 + 1];
  half8 h;
  h[0] = (_Float16)a.x; h[1] = (_Float16)a.y; h[2] = (_Float16)a.z; h[3] = (_Float16)a.w;
  h[4] = (_Float16)b.x; h[5] = (_Float16)b.y; h[6] = (_Float16)b.z; h[7] = (_Float16)b.w;
  ((half8*)out)[i] = h;
}

// ================= MFMA GEMM =================================================

__device__ __forceinline__ void gload16(const _Float16* g, _Float16* l) {
  __builtin_amdgcn_global_load_lds(
      (const __attribute__((address_space(1))) unsigned int*)g,
      (__attribute__((address_space(3))) unsigned int*)l, 16, 0, 0);
}

// C[M x 256] = A @ B^T  (B stored n-major [256][K] fp16).
// NKT = K/64.  NKT==8: A = concat_k(A0, A1) (two [M][256] buffers).
// EPI 0: O1 = C                                   (u' = r1@Pm + r2@Q)
// EPI 1: z = C + bias0; O1 = z + 0.1*bias1; O2 = tanh(z)      (input layer)
// EPI 2: v' = C - O2; u = Uu; O1 = u + 0.1*bias1; O2 = (v' + 10*tanh(u))/11
template <int NKT, int EPI>
__global__ __launch_bounds__(256) void k_mm(
    const _Float16* __restrict__ A0, const _Float16* __restrict__ A1,
    const _Float16* __restrict__ Bm,
    _Float16* __restrict__ O1, _Float16* __restrict__ O2,
    const _Float16* __restrict__ Uu,
    const float* __restrict__ bias0, const float* __restrict__ bias1) {
  __shared__ __align__(16) _Float16 As[128 * 64];
  __shared__ __align__(16) _Float16 Bs[128 * 64];
  const int tid = threadIdx.x;
  const int wave = tid >> 6, lane = tid & 63;
  const int quad = lane >> 4, l16 = lane & 15;
  const int wm = wave >> 1, wn = wave & 1;
  const int m0 = blockIdx.y * 128, n0 = blockIdx.x * 128;
  const int BSTR = NKT * 64;

  f32x4 acc[4][4];
#pragma unroll
  for (int mi = 0; mi < 4; ++mi)
#pragma unroll
    for (int ni = 0; ni < 4; ++ni) acc[mi][ni] = (f32x4){0.f, 0.f, 0.f, 0.f};

  // per-lane staging slot decode (slot = chunk of 8 fp16 = 16 B)
  // LDS is linear; the GLOBAL chunk index is XOR-swizzled so frag reads are
  // bank-conflict-free without padding (padding would break global_load_lds).
  for (int kt = 0; kt < NKT; ++kt) {
    const _Float16* Ab = (NKT == 8 && kt >= 4) ? A1 : A0;
    const int ak0 = (NKT == 8 ? (kt & 3) : kt) * 64;
    const int bk0 = kt * 64;
    __syncthreads();  // previous iter's compute done before LDS overwrite
#pragma unroll
    for (int i = 0; i < 4; ++i) {
      const int s = (i * 4 + wave) * 64 + lane;
      const int row = s >> 3;
      const int k8 = (s & 7) ^ (row & 7);
      _Float16* ldsb = &As[(i * 4 + wave) * 512];  // wave-uniform base
      gload16(Ab + (size_t)(m0 + row) * 256 + ak0 + k8 * 8, ldsb);
      _Float16* ldsb2 = &Bs[(i * 4 + wave) * 512];
      gload16(Bm + (size_t)(n0 + row) * BSTR + bk0 + k8 * 8, ldsb2);
    }
    __builtin_amdgcn_s_waitcnt(0);  // drain vmcnt (global_load_lds)
    __syncthreads();

    half8 af[4][2], bf[4][2];
#pragma unroll
    for (int mi = 0; mi < 4; ++mi)
#pragma unroll
      for (int kh = 0; kh < 2; ++kh) {
        const int ra = wm * 64 + mi * 16 + l16;
        af[mi][kh] = *(const half8*)&As[ra * 64 + (((kh * 4 + quad) ^ (ra & 7)) * 8)];
        const int rb = wn * 64 + mi * 16 + l16;
        bf[mi][kh] = *(const half8*)&Bs[rb * 64 + (((kh * 4 + quad) ^ (rb & 7)) * 8)];
      }
#pragma unroll
    for (int kh = 0; kh < 2; ++kh)
#pragma unroll
      for (int mi = 0; mi < 4; ++mi)
#pragma unroll
        for (int ni = 0; ni < 4; ++ni)
          acc[mi][ni] = __builtin_amdgcn_mfma_f32_16x16x32_f16(
              af[mi][kh], bf[ni][kh], acc[mi][ni], 0, 0, 0);
  }

  // epilogue: C element (row = quad*4+r, col = l16) per 16x16 tile
#pragma unroll
  for (int mi = 0; mi < 4; ++mi)
#pragma unroll
    for (int ni = 0; ni < 4; ++ni) {
      const int col = n0 + wn * 64 + ni * 16 + l16;
#pragma unroll
      for (int r = 0; r < 4; ++r) {
        const int row = m0 + wm * 64 + mi * 16 + quad * 4 + r;
        const size_t off = (size_t)row * 256 + col;
        const float v = acc[mi][ni][r];
        if (EPI == 0) {
          O1[off] = (_Float16)v;
        } else if (EPI == 1) {
          const float z = v + bias0[col];
          O1[off] = (_Float16)(z + DTC * bias1[col]);
          O2[off] = (_Float16)tanhf(z);  // r2 = (tanh z + 10 tanh z)/11 = tanh z
        } else {
          const float r2o = (float)O2[off];
          const float vp = v - r2o;                 // v' = u'@Rm - r2
          const float uv = (float)Uu[off];          // u'
          O1[off] = (_Float16)(uv + DTC * bias1[col]);
          O2[off] = (_Float16)((vp + 10.f * tanhf(uv)) * (1.f / 11.f));
        }
      }
    }
}

// logits = Z @ Wo^T + bo ; softmax over 10 classes. One wave per row.
__global__ __launch_bounds__(256) void k_out(const _Float16* __restrict__ Z,
                                             const float* __restrict__ Wo,
                                             const float* __restrict__ bo,
                                             float* __restrict__ out) {
  const int wave = threadIdx.x >> 6;
  const int lane = threadIdx.x & 63;
  const int row = blockIdx.x * 4 + wave;
  const half4v z4 = *(const half4v*)&Z[(size_t)row * 256 + lane * 4];
  const float zx = (float)z4[0], zy = (float)z4[1], zz = (float)z4[2], zw = (float)z4[3];
  float logit[10];
#pragma unroll
  for (int c = 0; c < 10; ++c) {
    const float4 w = *(const float4*)&Wo[c * 256 + lane * 4];
    float p = zx * w.x + zy * w.y + zz * w.z + zw * w.w;
#pragma unroll
    for (int off = 32; off; off >>= 1) p += __shfl_xor(p, off, 64);
    logit[c] = p + bo[c];
  }
  float m = logit[0];
#pragma unroll
  for (int c = 1; c < 10; ++c) m = fmaxf(m, logit[c]);
  float e[10];
  float s = 0.f;
#pragma unroll
  for (int c = 0; c < 10; ++c) { e[c] = expf(logit[c] - m); s += e[c]; }
  const float inv = 1.f / s;
  if (lane < 10) out[(size_t)row * 10 + lane] = e[lane] * inv;
}

// ================= launcher ==================================================

extern "C" void kernel_launch(void* const* d_in, const int* in_sizes, int n_in,
                              void* d_out, int out_size, void* d_ws, size_t ws_size,
                              hipStream_t stream) {
  const float* x  = (const float*)d_in[0];
  const float* Wi = (const float*)d_in[1];
  const float* bi = (const float*)d_in[2];
  const float* W[4] = {(const float*)d_in[3], (const float*)d_in[5],
                       (const float*)d_in[7], (const float*)d_in[9]};
  const float* b[4] = {(const float*)d_in[4], (const float*)d_in[6],
                       (const float*)d_in[8], (const float*)d_in[10]};
  const float* Wo = (const float*)d_in[11];
  const float* bo = (const float*)d_in[12];
  float* out = (float*)d_out;

  const int Bsz = in_sizes[0] / 256;  // 32768

  _Float16* hb = (_Float16*)d_ws;
  _Float16* Xh   = hb;                    // 8388608
  _Float16* R1h  = hb + 8388608;
  _Float16* R2h  = hb + 16777216;
  _Float16* Uh   = hb + 25165824;
  _Float16* WiTh = hb + 33554432;         // 65536
  _Float16* PQh  = hb + 33619968;         // 4*131072
  _Float16* RmTh = hb + 34144256;         // 4*65536
  float* fb = (float*)(hb + 34406400);
  float* E  = fb;                         // 4*65536 each
  float* Pa = fb + 262144;
  float* Pb = fb + 524288;

  // ---- precompute (tiny) ----
  const dim3 blk16(16, 16);
  const dim3 grd16(16, 16, 4);
  k_compE<<<grd16, blk16, 0, stream>>>(W[0], W[1], W[2], W[3], E);
  k_initP<<<(4 * 65536) / 256, 256, 0, stream>>>(E, Pa);
  k_neumann<<<grd16, blk16, 0, stream>>>(E, Pa, Pb);
  k_neumann<<<grd16, blk16, 0, stream>>>(E, Pb, Pa);
  k_neumann<<<grd16, blk16, 0, stream>>>(E, Pa, Pb);   // err ~ ||E||^5 ~ 4e-10
  k_finish<<<grd16, blk16, 0, stream>>>(W[0], W[1], W[2], W[3], Pb, PQh, RmTh);
  k_cast<<<32, 256, 0, stream>>>(Wi, WiTh);            // Wi is already n-major
  k_cast<<<(Bsz * 256) / (256 * 8), 256, 0, stream>>>(x, Xh);

  // ---- batch pipeline ----
  const dim3 gg(2, Bsz / 128);
  // input layer: z = x@Wi^T + bi ; R1 = z + 0.1*b1 ; R2 = tanh(z)
  k_mm<4, 1><<<gg, 256, 0, stream>>>(Xh, nullptr, WiTh, R1h, R2h, nullptr, bi, b[0]);

  for (int l = 0; l < 4; ++l) {
    // u' = r1@Pm + r2@Q   (K=512)
    k_mm<8, 0><<<gg, 256, 0, stream>>>(R1h, R2h, PQh + (size_t)l * 131072,
                                       Uh, nullptr, nullptr, nullptr, nullptr);
    if (l < 3) {
      // v' = u'@Rm - r2 ; then next layer's r1,r2 fused
      k_mm<4, 2><<<gg, 256, 0, stream>>>(Uh, nullptr, RmTh + (size_t)l * 65536,
                                         R1h, R2h, Uh, nullptr, b[l + 1]);
    }
  }
  k_out<<<Bsz / 4, 256, 0, stream>>>(Uh, Wo, bo, out);
}

// Round 3
// 267.093 us; speedup vs baseline: 3.7685x; 1.2991x over previous
//
#include <hip/hip_runtime.h>
#include <math.h>

#define DTC 0.1f

typedef _Float16 half8 __attribute__((ext_vector_type(8)));
typedef _Float16 half4v __attribute__((ext_vector_type(4)));
typedef float f32x4 __attribute__((ext_vector_type(4)));

// ================= precompute (fp32, tiny) ===================================

// E = DT^2 * W * W^T   (per layer)
__global__ void k_compE(const float* __restrict__ W0, const float* __restrict__ W1,
                        const float* __restrict__ W2, const float* __restrict__ W3,
                        float* __restrict__ E) {
  const float* Ws[4] = {W0, W1, W2, W3};
  const float* W = Ws[blockIdx.z];
  float* Eo = E + (size_t)blockIdx.z * 65536;
  __shared__ float As[16][17], Bs[16][17];
  const int tx = threadIdx.x, ty = threadIdx.y;
  const int i = blockIdx.y * 16 + ty;
  const int j = blockIdx.x * 16 + tx;
  float acc = 0.f;
  for (int k0 = 0; k0 < 256; k0 += 16) {
    As[ty][tx] = W[i * 256 + k0 + tx];
    Bs[ty][tx] = W[(blockIdx.x * 16 + ty) * 256 + k0 + tx];
    __syncthreads();
#pragma unroll
    for (int k = 0; k < 16; ++k) acc += As[ty][k] * Bs[tx][k];
    __syncthreads();
  }
  Eo[i * 256 + j] = 0.01f * acc;
}

// T = E @ E
__global__ void k_sqE(const float* __restrict__ E, float* __restrict__ T) {
  const int l = blockIdx.z;
  const float* El = E + (size_t)l * 65536;
  float* Tl = T + (size_t)l * 65536;
  __shared__ float As[16][17], Bs[16][17];
  const int tx = threadIdx.x, ty = threadIdx.y;
  const int i = blockIdx.y * 16 + ty;
  const int j = blockIdx.x * 16 + tx;
  float acc = 0.f;
  for (int k0 = 0; k0 < 256; k0 += 16) {
    As[ty][tx] = El[i * 256 + k0 + tx];
    Bs[ty][tx] = El[(k0 + ty) * 256 + j];
    __syncthreads();
#pragma unroll
    for (int k = 0; k < 16; ++k) acc += As[ty][k] * Bs[k][tx];
    __syncthreads();
  }
  Tl[i * 256 + j] = acc;
}

// P = I - E + T - T@E + T@T   (Neumann to E^4; ||E||~1e-2 so err ~1e-10)
__global__ void k_compP(const float* __restrict__ E, const float* __restrict__ T,
                        float* __restrict__ P) {
  const int l = blockIdx.z;
  const float* El = E + (size_t)l * 65536;
  const float* Tl = T + (size_t)l * 65536;
  float* Pl = P + (size_t)l * 65536;
  __shared__ float As[16][17], B1s[16][17], B2s[16][17];
  const int tx = threadIdx.x, ty = threadIdx.y;
  const int i = blockIdx.y * 16 + ty;
  const int j = blockIdx.x * 16 + tx;
  float acc1 = 0.f, acc2 = 0.f;
  for (int k0 = 0; k0 < 256; k0 += 16) {
    As[ty][tx]  = Tl[i * 256 + k0 + tx];
    B1s[ty][tx] = El[(k0 + ty) * 256 + j];
    B2s[ty][tx] = Tl[(k0 + ty) * 256 + j];
    __syncthreads();
#pragma unroll
    for (int k = 0; k < 16; ++k) {
      acc1 += As[ty][k] * B1s[k][tx];
      acc2 += As[ty][k] * B2s[k][tx];
    }
    __syncthreads();
  }
  const int ij = i * 256 + j;
  Pl[ij] = (i == j ? 1.f : 0.f) - El[ij] + Tl[ij] - acc1 + acc2;
}

// Q = DT * W^T @ P ; emit frag-packed fp16 weights:
//   PQP[l]: B[n][k], K=512: k<256 -> -P[k][n], k>=256 -> Q[k-256][n]   (NKT=16)
//   RmP[l] (l<3): B[n][k] = -0.9*W[k][n]                               (NKT=8)
// packed idx = ((ntile*NKT + kt)*64 + (quad*16 + l16))*8 + j
//   with n = ntile*16 + l16, k = kt*32 + quad*8 + j
__global__ void k_finishPack(const float* __restrict__ W0, const float* __restrict__ W1,
                             const float* __restrict__ W2, const float* __restrict__ W3,
                             const float* __restrict__ Pmat, _Float16* __restrict__ PQP,
                             _Float16* __restrict__ RmP) {
  const float* Ws[4] = {W0, W1, W2, W3};
  const int l = blockIdx.z;
  const float* W = Ws[l];
  const float* P = Pmat + (size_t)l * 65536;
  __shared__ float As[16][17], Bs[16][17];
  const int tx = threadIdx.x, ty = threadIdx.y;
  const int i = blockIdx.y * 16 + ty;   // k-index
  const int j = blockIdx.x * 16 + tx;   // n-index
  float acc = 0.f;
  for (int m0 = 0; m0 < 256; m0 += 16) {
    As[ty][tx] = W[(m0 + ty) * 256 + blockIdx.y * 16 + tx];  // W[m][i-range]
    Bs[ty][tx] = P[(m0 + ty) * 256 + j];                     // P[m][j]
    __syncthreads();
#pragma unroll
    for (int m = 0; m < 16; ++m) acc += As[m][ty] * Bs[m][tx];
    __syncthreads();
  }
  const int ntile = j >> 4, l16 = j & 15;
  const int kt = i >> 5, quad = (i >> 3) & 3, jj = i & 7;
  const int lanebase = quad * 16 + l16;
  _Float16* PQl = PQP + (size_t)l * 131072;
  PQl[((ntile * 16 + kt) * 64 + lanebase) * 8 + jj]       = (_Float16)(-P[i * 256 + j]);
  PQl[((ntile * 16 + 8 + kt) * 64 + lanebase) * 8 + jj]   = (_Float16)(DTC * acc);
  if (l < 3)
    RmP[(size_t)l * 65536 + ((ntile * 8 + kt) * 64 + lanebase) * 8 + jj] =
        (_Float16)(-0.9f * W[i * 256 + j]);
}

// pack Wi (fp32 [n][k]) -> frag-packed fp16, NKT=8
__global__ void k_packWi(const float* __restrict__ Wi, _Float16* __restrict__ WiP) {
  const int idx = blockIdx.x * 256 + threadIdx.x;
  const int n = idx >> 8, k = idx & 255;
  const int ntile = n >> 4, l16 = n & 15;
  const int kt = k >> 5, quad = (k >> 3) & 3, jj = k & 7;
  WiP[((ntile * 8 + kt) * 64 + (quad * 16 + l16)) * 8 + jj] = (_Float16)Wi[n * 256 + k];
}

// ================= fused persistent batch kernel =============================
// Per block: 64 batch rows. r1/r2 live in LDS (XOR-swizzled 16B chunks along k).
// All weights read as coalesced packed fragments from global (L2-resident).
// No barriers inside any K-loop.

__device__ __forceinline__ void lds_w16(_Float16* base, int row, int col, float v) {
  const int chunk = (col >> 3) ^ (row & 7);
  *(_Float16*)((char*)base + row * 512 + (chunk << 4) + (col & 7) * 2) = (_Float16)v;
}
__device__ __forceinline__ float lds_r16(const _Float16* base, int row, int col) {
  const int chunk = (col >> 3) ^ (row & 7);
  return (float)*(const _Float16*)((const char*)base + row * 512 + (chunk << 4) + (col & 7) * 2);
}

// acc[mi*4+ni] over wave tile 64 rows x 64 cols (cols = wave*64 ..).
template <int NKT, bool DUAL>
__device__ __forceinline__ void gemm_k(const _Float16* __restrict__ Bp,
                                       const _Float16* A1, const _Float16* A2,
                                       f32x4* acc, int wave, int lane, int quad, int l16) {
#pragma unroll
  for (int kt = 0; kt < NKT; ++kt) {
    const _Float16* Ab = (DUAL && kt >= 8) ? A2 : A1;
    const int akt = DUAL ? (kt & 7) : kt;
    half8 bf[4], af[4];
#pragma unroll
    for (int ni = 0; ni < 4; ++ni) {
      const int ntile = wave * 4 + ni;
      bf[ni] = *(const half8*)&Bp[(((ntile * NKT + kt) * 64) + lane) * 8];
    }
#pragma unroll
    for (int mi = 0; mi < 4; ++mi) {
      const int row = mi * 16 + l16;
      const int chunk = (akt * 4 + quad) ^ (row & 7);
      af[mi] = *(const half8*)((const char*)Ab + row * 512 + (chunk << 4));
    }
#pragma unroll
    for (int mi = 0; mi < 4; ++mi)
#pragma unroll
      for (int ni = 0; ni < 4; ++ni)
        acc[mi * 4 + ni] = __builtin_amdgcn_mfma_f32_16x16x32_f16(
            af[mi], bf[ni], acc[mi * 4 + ni], 0, 0, 0);
  }
}

__global__ __launch_bounds__(256, 2) void k_fused(
    const float* __restrict__ x, const _Float16* __restrict__ WiP,
    const _Float16* __restrict__ PQP, const _Float16* __restrict__ RmP,
    const float* __restrict__ bi, const float* __restrict__ b1,
    const float* __restrict__ b2, const float* __restrict__ b3,
    const float* __restrict__ b4, const float* __restrict__ Wo,
    const float* __restrict__ bo, float* __restrict__ out) {
  __shared__ __align__(16) _Float16 A1[64 * 256];
  __shared__ __align__(16) _Float16 A2[64 * 256];
  const int tid = threadIdx.x;
  const int wave = tid >> 6, lane = tid & 63;
  const int quad = lane >> 4, l16 = lane & 15;
  const int m0 = blockIdx.x * 64;
  const float* bs[4] = {b1, b2, b3, b4};

  // ---- stage x: fp32 HBM -> fp16 swizzled LDS (A1) ----
#pragma unroll
  for (int it = 0; it < 16; ++it) {
    const int idx = it * 256 + tid;  // 0..4095
    const int row = idx >> 6, c4 = idx & 63;
    const float4 v = *(const float4*)&x[(size_t)(m0 + row) * 256 + c4 * 4];
    half4v h;
    h[0] = (_Float16)v.x; h[1] = (_Float16)v.y; h[2] = (_Float16)v.z; h[3] = (_Float16)v.w;
    const int chunk = (c4 >> 1) ^ (row & 7), part = c4 & 1;
    *(half4v*)((char*)A1 + row * 512 + (chunk << 4) + (part << 3)) = h;
  }
  __syncthreads();

  f32x4 acc[16];
  const f32x4 zero = {0.f, 0.f, 0.f, 0.f};

  // ---- GEMM0: z = x @ WiT ; r1 = z + bi + 0.1*b1 -> A1 ; r2 = tanh(z+bi) -> A2
#pragma unroll
  for (int t = 0; t < 16; ++t) acc[t] = zero;
  gemm_k<8, false>(WiP, A1, A1, acc, wave, lane, quad, l16);
  __syncthreads();
#pragma unroll
  for (int ni = 0; ni < 4; ++ni) {
    const int col = wave * 64 + ni * 16 + l16;
    const float bicol = bi[col], b1col = b1[col];
#pragma unroll
    for (int mi = 0; mi < 4; ++mi)
#pragma unroll
      for (int r = 0; r < 4; ++r) {
        const int row = mi * 16 + quad * 4 + r;
        const float z = acc[mi * 4 + ni][r] + bicol;
        lds_w16(A1, row, col, z + DTC * b1col);
        lds_w16(A2, row, col, tanhf(z));
      }
  }
  __syncthreads();

  // ---- 4 transport layers ----
#pragma unroll 1
  for (int l = 0; l < 4; ++l) {
    // u' = r1@Pm + r2@Q   (K=512, A from A1 then A2)
#pragma unroll
    for (int t = 0; t < 16; ++t) acc[t] = zero;
    gemm_k<16, true>(PQP + (size_t)l * 131072, A1, A2, acc, wave, lane, quad, l16);
    __syncthreads();
#pragma unroll
    for (int ni = 0; ni < 4; ++ni) {
      const int col = wave * 64 + ni * 16 + l16;
#pragma unroll
      for (int mi = 0; mi < 4; ++mi)
#pragma unroll
        for (int r = 0; r < 4; ++r)
          lds_w16(A1, mi * 16 + quad * 4 + r, col, acc[mi * 4 + ni][r]);
    }
    __syncthreads();
    if (l < 3) {
      // v' = u'@Rm - r2 ; next r1 = u' + 0.1*b[l+1] ; next r2 = (v'+10 tanh u')/11
#pragma unroll
      for (int t = 0; t < 16; ++t) acc[t] = zero;
      gemm_k<8, false>(RmP + (size_t)l * 65536, A1, A1, acc, wave, lane, quad, l16);
      __syncthreads();
      const float* bn = bs[l + 1];
#pragma unroll
      for (int ni = 0; ni < 4; ++ni) {
        const int col = wave * 64 + ni * 16 + l16;
        const float bcol = bn[col];
#pragma unroll
        for (int mi = 0; mi < 4; ++mi)
#pragma unroll
          for (int r = 0; r < 4; ++r) {
            const int row = mi * 16 + quad * 4 + r;
            const float uv = lds_r16(A1, row, col);
            const float r2o = lds_r16(A2, row, col);
            const float vp = acc[mi * 4 + ni][r] - r2o;
            lds_w16(A1, row, col, uv + DTC * bcol);
            lds_w16(A2, row, col, (vp + 10.f * tanhf(uv)) * (1.f / 11.f));
          }
      }
      __syncthreads();
    }
  }

  // ---- output head: logits = z@Wo^T + bo ; softmax(10) ; z is in A1 ----
  float4 wo[10];
  float boc[10];
#pragma unroll
  for (int c = 0; c < 10; ++c) {
    wo[c] = *(const float4*)&Wo[c * 256 + lane * 4];
    boc[c] = bo[c];
  }
#pragma unroll 1
  for (int rr = 0; rr < 16; ++rr) {
    const int row = wave * 16 + rr;
    const int col = lane * 4;
    const int chunk = (lane >> 1) ^ (row & 7), part = lane & 1;
    const half4v z4 = *(const half4v*)((const char*)A1 + row * 512 + (chunk << 4) + (part << 3));
    const float zx = (float)z4[0], zy = (float)z4[1], zz = (float)z4[2], zw = (float)z4[3];
    float logit[10];
#pragma unroll
    for (int c = 0; c < 10; ++c) {
      float p = zx * wo[c].x + zy * wo[c].y + zz * wo[c].z + zw * wo[c].w;
#pragma unroll
      for (int off = 32; off; off >>= 1) p += __shfl_xor(p, off, 64);
      logit[c] = p + boc[c];
    }
    float mx = logit[0];
#pragma unroll
    for (int c = 1; c < 10; ++c) mx = fmaxf(mx, logit[c]);
    float s = 0.f, e[10];
#pragma unroll
    for (int c = 0; c < 10; ++c) { e[c] = expf(logit[c] - mx); s += e[c]; }
    const float inv = 1.f / s;
    float v = 0.f;
#pragma unroll
    for (int c = 0; c < 10; ++c) v = (lane == c) ? e[c] * inv : v;
    if (lane < 10) out[(size_t)(m0 + row) * 10 + lane] = v;
  }
}

// ================= launcher ==================================================

extern "C" void kernel_launch(void* const* d_in, const int* in_sizes, int n_in,
                              void* d_out, int out_size, void* d_ws, size_t ws_size,
                              hipStream_t stream) {
  const float* x  = (const float*)d_in[0];
  const float* Wi = (const float*)d_in[1];
  const float* bi = (const float*)d_in[2];
  const float* W[4] = {(const float*)d_in[3], (const float*)d_in[5],
                       (const float*)d_in[7], (const float*)d_in[9]};
  const float* b[4] = {(const float*)d_in[4], (const float*)d_in[6],
                       (const float*)d_in[8], (const float*)d_in[10]};
  const float* Wo = (const float*)d_in[11];
  const float* bo = (const float*)d_in[12];
  float* out = (float*)d_out;

  const int Bsz = in_sizes[0] / 256;  // 32768

  _Float16* hb = (_Float16*)d_ws;
  _Float16* WiP = hb;                       // 65536 halves
  _Float16* PQP = hb + 65536;               // 4*131072
  _Float16* RmP = hb + 65536 + 524288;      // 3*65536
  float* fb = (float*)(hb + 65536 + 524288 + 196608);
  float* E = fb;                            // 4*65536 each
  float* T = fb + 262144;
  float* P = fb + 524288;

  const dim3 blk16(16, 16);
  const dim3 grd16(16, 16, 4);
  k_compE<<<grd16, blk16, 0, stream>>>(W[0], W[1], W[2], W[3], E);
  k_sqE<<<grd16, blk16, 0, stream>>>(E, T);
  k_compP<<<grd16, blk16, 0, stream>>>(E, T, P);
  k_finishPack<<<grd16, blk16, 0, stream>>>(W[0], W[1], W[2], W[3], P, PQP, RmP);
  k_packWi<<<256, 256, 0, stream>>>(Wi, WiP);

  k_fused<<<Bsz / 64, 256, 0, stream>>>(x, WiP, PQP, RmP, bi, b[0], b[1], b[2], b[3],
                                        Wo, bo, out);
}

// Round 4
// 235.075 us; speedup vs baseline: 4.2817x; 1.1362x over previous
//
#include <hip/hip_runtime.h>
#include <math.h>

#define DTC 0.1f

typedef _Float16 half8 __attribute__((ext_vector_type(8)));
typedef float f32x4 __attribute__((ext_vector_type(4)));

__device__ __forceinline__ float fast_tanh(float x) {
  // tanh(x) = 1 - 2/(exp(2x)+1); exact at +-inf saturation
  const float e = __expf(2.f * x);
  const float r = __builtin_amdgcn_rcpf(e + 1.f);
  return fmaf(-2.f, r, 1.f);
}

// ================= precompute: pack + tiny MFMA chain ========================
// Packed B-frag format (NKT k-tiles of 32): idx = ((ntile*NKT+kt)*64 + quad*16+l16)*8 + jj
//   holds B[n = ntile*16+l16][k = kt*32+quad*8+jj]

__global__ __launch_bounds__(256) void k_pack(
    const float* __restrict__ W0, const float* __restrict__ W1,
    const float* __restrict__ W2, const float* __restrict__ W3,
    const float* __restrict__ Wi, const float* __restrict__ Wo,
    _Float16* __restrict__ Wh, _Float16* __restrict__ Wt,
    _Float16* __restrict__ RmP, _Float16* __restrict__ WiP,
    _Float16* __restrict__ WoP) {
  const float* Ws[4] = {W0, W1, W2, W3};
  const int bid = blockIdx.x, tid = threadIdx.x;
  if (bid < 1024) {
    const int idx = bid * 256 + tid;
    const int l = idx >> 16, mk = idx & 65535, m = mk >> 8, k = mk & 255;
    const float w = Ws[l][m * 256 + k];
    const _Float16 h = (_Float16)w;
    Wh[idx] = h;
    Wt[(size_t)l * 65536 + k * 256 + m] = h;
    if (l < 3)  // Rm = -0.9*W, packed as B[n=k][k'=m], NKT=8
      RmP[(size_t)l * 65536 +
          ((((k >> 4) * 8 + (m >> 5)) * 64) + ((m >> 3) & 3) * 16 + (k & 15)) * 8 + (m & 7)] =
          (_Float16)(-0.9f * w);
  } else if (bid < 1280) {
    const int idx = (bid - 1024) * 256 + tid;
    const int n = idx >> 8, k = idx & 255;
    WiP[(((n >> 4) * 8 + (k >> 5)) * 64 + ((k >> 3) & 3) * 16 + (n & 15)) * 8 + (k & 7)] =
        (_Float16)Wi[idx];
  } else {
    const int idx = (bid - 1280) * 256 + tid;  // 0..4095
    const int n = idx >> 8, k = idx & 255;     // n = class (pad to 16)
    WoP[((k >> 5) * 64 + ((k >> 3) & 3) * 16 + n) * 8 + (k & 7)] =
        (_Float16)((n < 10) ? Wo[n * 256 + k] : 0.f);
  }
}

// crm[l][j] = 0.1*(b_{l+1} @ Rm_l)[j] = -0.09 * sum_k b[k]*W_l[k][j]
__global__ __launch_bounds__(256) void k_crm(const float* __restrict__ W0,
                                             const float* __restrict__ W1,
                                             const float* __restrict__ W2,
                                             const float* __restrict__ b2,
                                             const float* __restrict__ b3,
                                             const float* __restrict__ b4,
                                             float* __restrict__ crm) {
  const float* Ws[3] = {W0, W1, W2};
  const float* bs[3] = {b2, b3, b4};
  const int l = blockIdx.x, j = threadIdx.x;
  const float* W = Ws[l];
  const float* b = bs[l];
  float s = 0.f;
#pragma unroll 8
  for (int k = 0; k < 256; ++k) s = fmaf(b[k], W[k * 256 + j], s);
  crm[l * 256 + j] = -0.09f * s;
}

// C = scale * A @ B^T  (A row-major, B n-major = row-major; 256x256 per layer)
__global__ __launch_bounds__(256) void k_smm(const _Float16* __restrict__ A,
                                             const _Float16* __restrict__ B,
                                             _Float16* __restrict__ C, float scale) {
  const int tid = threadIdx.x, wave = tid >> 6, lane = tid & 63;
  const int quad = lane >> 4, l16 = lane & 15;
  const int l = blockIdx.z;
  const _Float16* Al = A + (size_t)l * 65536;
  const _Float16* Bl = B + (size_t)l * 65536;
  _Float16* Cl = C + (size_t)l * 65536;
  const int m0 = blockIdx.y * 64 + wave * 16, n0 = blockIdx.x * 64;
  f32x4 acc[4] = {};
#pragma unroll
  for (int kt = 0; kt < 8; ++kt) {
    const half8 af = *(const half8*)&Al[(m0 + l16) * 256 + kt * 32 + quad * 8];
#pragma unroll
    for (int ni = 0; ni < 4; ++ni) {
      const half8 bf = *(const half8*)&Bl[(n0 + ni * 16 + l16) * 256 + kt * 32 + quad * 8];
      acc[ni] = __builtin_amdgcn_mfma_f32_16x16x32_f16(af, bf, acc[ni], 0, 0, 0);
    }
  }
#pragma unroll
  for (int ni = 0; ni < 4; ++ni)
#pragma unroll
    for (int r = 0; r < 4; ++r)
      Cl[(m0 + quad * 4 + r) * 256 + n0 + ni * 16 + l16] = (_Float16)(scale * acc[ni][r]);
}

// P = I - E + T - T@E + T@T ; write Ph and scatter -P into PQP first half (kt 0..7)
__global__ __launch_bounds__(256) void k_pP(const _Float16* __restrict__ Eh,
                                            const _Float16* __restrict__ Th,
                                            _Float16* __restrict__ Ph,
                                            _Float16* __restrict__ PQP) {
  const int tid = threadIdx.x, wave = tid >> 6, lane = tid & 63;
  const int quad = lane >> 4, l16 = lane & 15;
  const int l = blockIdx.z;
  const _Float16* El = Eh + (size_t)l * 65536;
  const _Float16* Tl = Th + (size_t)l * 65536;
  _Float16* Pl = Ph + (size_t)l * 65536;
  _Float16* PQl = PQP + (size_t)l * 131072;
  const int m0 = blockIdx.y * 64 + wave * 16, n0 = blockIdx.x * 64;
  f32x4 a1[4] = {}, a2[4] = {};
#pragma unroll
  for (int kt = 0; kt < 8; ++kt) {
    const half8 af = *(const half8*)&Tl[(m0 + l16) * 256 + kt * 32 + quad * 8];
#pragma unroll
    for (int ni = 0; ni < 4; ++ni) {
      const half8 bfe = *(const half8*)&El[(n0 + ni * 16 + l16) * 256 + kt * 32 + quad * 8];
      const half8 bft = *(const half8*)&Tl[(n0 + ni * 16 + l16) * 256 + kt * 32 + quad * 8];
      a1[ni] = __builtin_amdgcn_mfma_f32_16x16x32_f16(af, bfe, a1[ni], 0, 0, 0);
      a2[ni] = __builtin_amdgcn_mfma_f32_16x16x32_f16(af, bft, a2[ni], 0, 0, 0);
    }
  }
#pragma unroll
  for (int ni = 0; ni < 4; ++ni)
#pragma unroll
    for (int r = 0; r < 4; ++r) {
      const int row = m0 + quad * 4 + r, col = n0 + ni * 16 + l16;
      const float e = (float)El[row * 256 + col];
      const float t = (float)Tl[row * 256 + col];
      const float p = (row == col ? 1.f : 0.f) - e + t - a1[ni][r] + a2[ni][r];
      Pl[row * 256 + col] = (_Float16)p;
      // scatter -P[k=row][n=col] into packed (NKT=16, kt = row>>5)
      PQl[(((col >> 4) * 16 + (row >> 5)) * 64 + ((row >> 3) & 3) * 16 + (col & 15)) * 8 +
          (row & 7)] = (_Float16)(-p);
    }
}

// Q = 0.1 * Wt @ Ph^T(sym) ; scatter into PQP second half (kt 8..15)
__global__ __launch_bounds__(256) void k_pQ(const _Float16* __restrict__ Wt,
                                            const _Float16* __restrict__ Ph,
                                            _Float16* __restrict__ PQP) {
  const int tid = threadIdx.x, wave = tid >> 6, lane = tid & 63;
  const int quad = lane >> 4, l16 = lane & 15;
  const int l = blockIdx.z;
  const _Float16* Al = Wt + (size_t)l * 65536;
  const _Float16* Bl = Ph + (size_t)l * 65536;
  _Float16* PQl = PQP + (size_t)l * 131072;
  const int m0 = blockIdx.y * 64 + wave * 16, n0 = blockIdx.x * 64;
  f32x4 acc[4] = {};
#pragma unroll
  for (int kt = 0; kt < 8; ++kt) {
    const half8 af = *(const half8*)&Al[(m0 + l16) * 256 + kt * 32 + quad * 8];
#pragma unroll
    for (int ni = 0; ni < 4; ++ni) {
      const half8 bf = *(const half8*)&Bl[(n0 + ni * 16 + l16) * 256 + kt * 32 + quad * 8];
      acc[ni] = __builtin_amdgcn_mfma_f32_16x16x32_f16(af, bf, acc[ni], 0, 0, 0);
    }
  }
#pragma unroll
  for (int ni = 0; ni < 4; ++ni)
#pragma unroll
    for (int r = 0; r < 4; ++r) {
      const int row = m0 + quad * 4 + r, col = n0 + ni * 16 + l16;
      PQl[(((col >> 4) * 16 + 8 + (row >> 5)) * 64 + ((row >> 3) & 3) * 16 + (col & 15)) * 8 +
          (row & 7)] = (_Float16)(DTC * acc[ni][r]);
    }
}

// ================= fused persistent batch kernel =============================

__device__ __forceinline__ void lds_w16(_Float16* base, int row, int col, float v) {
  const int chunk = (col >> 3) ^ (row & 7);
  *(_Float16*)((char*)base + row * 512 + (chunk << 4) + (col & 7) * 2) = (_Float16)v;
}
__device__ __forceinline__ float lds_r16(const _Float16* base, int row, int col) {
  const int chunk = (col >> 3) ^ (row & 7);
  return (float)*(const _Float16*)((const char*)base + row * 512 + (chunk << 4) + (col & 7) * 2);
}

// wave tile 64 rows x 64 cols; ring-buffered depth-2 prefetch of A(LDS)+B(global)
template <int NKT, bool DUAL>
__device__ __forceinline__ void gemm_k(const _Float16* __restrict__ Bp,
                                       const _Float16* A1, const _Float16* A2,
                                       f32x4* acc, int wave, int lane, int quad, int l16) {
  half8 bf[3][4], af[3][4];
  auto loadB = [&](int kt, int s) {
#pragma unroll
    for (int ni = 0; ni < 4; ++ni)
      bf[s][ni] = *(const half8*)&Bp[(((wave * 4 + ni) * NKT + kt) * 64 + lane) * 8];
  };
  auto loadA = [&](int kt, int s) {
    const _Float16* Ab = (DUAL && kt >= 8) ? A2 : A1;
    const int akt = DUAL ? (kt & 7) : kt;
#pragma unroll
    for (int mi = 0; mi < 4; ++mi) {
      const int row = mi * 16 + l16;
      const int chunk = (akt * 4 + quad) ^ (row & 7);
      af[s][mi] = *(const half8*)((const char*)Ab + row * 512 + (chunk << 4));
    }
  };
  loadB(0, 0); loadA(0, 0);
  loadB(1, 1); loadA(1, 1);
#pragma unroll
  for (int kt = 0; kt < NKT; ++kt) {
    const int s = kt % 3;
    if (kt + 2 < NKT) {
      const int sp = (kt + 2) % 3;
      loadB(kt + 2, sp);
      loadA(kt + 2, sp);
    }
#pragma unroll
    for (int mi = 0; mi < 4; ++mi)
#pragma unroll
      for (int ni = 0; ni < 4; ++ni)
        acc[mi * 4 + ni] = __builtin_amdgcn_mfma_f32_16x16x32_f16(
            af[s][mi], bf[s][ni], acc[mi * 4 + ni], 0, 0, 0);
  }
}

__global__ __launch_bounds__(256, 2) void k_fused(
    const float* __restrict__ x, const _Float16* __restrict__ WiP,
    const _Float16* __restrict__ PQP, const _Float16* __restrict__ RmP,
    const _Float16* __restrict__ WoP, const float* __restrict__ bi,
    const float* __restrict__ b1, const float* __restrict__ b2,
    const float* __restrict__ b3, const float* __restrict__ b4,
    const float* __restrict__ crm, const float* __restrict__ bo,
    float* __restrict__ out) {
  __shared__ __align__(16) _Float16 A1[64 * 256];
  __shared__ __align__(16) _Float16 A2[64 * 256];
  const int tid = threadIdx.x;
  const int wave = tid >> 6, lane = tid & 63;
  const int quad = lane >> 4, l16 = lane & 15;
  const int m0 = blockIdx.x * 64;
  const float* bs[4] = {b1, b2, b3, b4};

  // ---- stage x: fp32 HBM -> fp16 swizzled LDS (A1) ----
#pragma unroll
  for (int it = 0; it < 16; ++it) {
    const int idx = it * 256 + tid;
    const int row = idx >> 6, c4 = idx & 63;
    const float4 v = *(const float4*)&x[(size_t)(m0 + row) * 256 + c4 * 4];
    const int chunk = (c4 >> 1) ^ (row & 7), part = c4 & 1;
    _Float16* p = (_Float16*)((char*)A1 + row * 512 + (chunk << 4) + (part << 3));
    p[0] = (_Float16)v.x; p[1] = (_Float16)v.y; p[2] = (_Float16)v.z; p[3] = (_Float16)v.w;
  }
  __syncthreads();

  f32x4 acc[16];
  const f32x4 zero = {0.f, 0.f, 0.f, 0.f};

  // ---- GEMM0: z = x@WiT ; A1 = r1 = z+bi+0.1*b1 ; A2 = r2 = tanh(z+bi) ----
#pragma unroll
  for (int t = 0; t < 16; ++t) acc[t] = zero;
  gemm_k<8, false>(WiP, A1, A1, acc, wave, lane, quad, l16);
  __syncthreads();
#pragma unroll
  for (int ni = 0; ni < 4; ++ni) {
    const int col = wave * 64 + ni * 16 + l16;
    const float bicol = bi[col], b1col = b1[col];
#pragma unroll
    for (int mi = 0; mi < 4; ++mi)
#pragma unroll
      for (int r = 0; r < 4; ++r) {
        const int row = mi * 16 + quad * 4 + r;
        const float z = acc[mi * 4 + ni][r] + bicol;
        lds_w16(A1, row, col, z + DTC * b1col);
        lds_w16(A2, row, col, fast_tanh(z));
      }
  }
  __syncthreads();

  // ---- 4 transport layers ----
#pragma unroll 1
  for (int l = 0; l < 4; ++l) {
    // u' = r1@Pm + r2@Q   (K=512)
#pragma unroll
    for (int t = 0; t < 16; ++t) acc[t] = zero;
    gemm_k<16, true>(PQP + (size_t)l * 131072, A1, A2, acc, wave, lane, quad, l16);
    __syncthreads();
    const float* bn = (l < 3) ? bs[l + 1] : nullptr;
#pragma unroll
    for (int ni = 0; ni < 4; ++ni) {
      const int col = wave * 64 + ni * 16 + l16;
      const float bcol = (l < 3) ? DTC * bn[col] : 0.f;
#pragma unroll
      for (int mi = 0; mi < 4; ++mi)
#pragma unroll
        for (int r = 0; r < 4; ++r)
          lds_w16(A1, mi * 16 + quad * 4 + r, col, acc[mi * 4 + ni][r] + bcol);
    }
    __syncthreads();
    if (l < 3) {
      // r1@Rm = u'@Rm + crm ; v' = u'@Rm - r2 ; new r2 = (v' + 10 tanh u')/11
#pragma unroll
      for (int t = 0; t < 16; ++t) acc[t] = zero;
      gemm_k<8, false>(RmP + (size_t)l * 65536, A1, A1, acc, wave, lane, quad, l16);
      const float* crml = crm + l * 256;
#pragma unroll
      for (int ni = 0; ni < 4; ++ni) {
        const int col = wave * 64 + ni * 16 + l16;
        const float ccol = crml[col];
        const float bcol = DTC * bs[l + 1][col];
#pragma unroll
        for (int mi = 0; mi < 4; ++mi)
#pragma unroll
          for (int r = 0; r < 4; ++r) {
            const int row = mi * 16 + quad * 4 + r;
            const float r1v = lds_r16(A1, row, col);
            const float uv = r1v - bcol;
            const float r2o = lds_r16(A2, row, col);
            const float vp = acc[mi * 4 + ni][r] - ccol - r2o;
            lds_w16(A2, row, col, (vp + 10.f * fast_tanh(uv)) * (1.f / 11.f));
          }
      }
      __syncthreads();
    }
  }
  __syncthreads();

  // ---- head: logits = z@Wo^T + bo (MFMA, classes padded to 16); softmax ----
  {
    f32x4 acch = zero;
#pragma unroll
    for (int kt = 0; kt < 8; ++kt) {
      const int row = wave * 16 + l16;
      const int chunk = (kt * 4 + quad) ^ (row & 7);
      const half8 af = *(const half8*)((const char*)A1 + row * 512 + (chunk << 4));
      const half8 bf = *(const half8*)&WoP[(kt * 64 + lane) * 8];
      acch = __builtin_amdgcn_mfma_f32_16x16x32_f16(af, bf, acch, 0, 0, 0);
    }
    const float bov = (l16 < 10) ? bo[l16] : -3.0e38f;
    float e[4], inv[4];
#pragma unroll
    for (int r = 0; r < 4; ++r) {
      float v = acch[r] + bov;
      float mx = v;
#pragma unroll
      for (int off = 1; off < 16; off <<= 1) mx = fmaxf(mx, __shfl_xor(mx, off, 64));
      e[r] = __expf(v - mx);
      float s = e[r];
#pragma unroll
      for (int off = 1; off < 16; off <<= 1) s += __shfl_xor(s, off, 64);
      inv[r] = __builtin_amdgcn_rcpf(s);
    }
    if (l16 < 10) {
#pragma unroll
      for (int r = 0; r < 4; ++r)
        out[(size_t)(m0 + wave * 16 + quad * 4 + r) * 10 + l16] = e[r] * inv[r];
    }
  }
}

// ================= launcher ==================================================

extern "C" void kernel_launch(void* const* d_in, const int* in_sizes, int n_in,
                              void* d_out, int out_size, void* d_ws, size_t ws_size,
                              hipStream_t stream) {
  const float* x  = (const float*)d_in[0];
  const float* Wi = (const float*)d_in[1];
  const float* bi = (const float*)d_in[2];
  const float* W[4] = {(const float*)d_in[3], (const float*)d_in[5],
                       (const float*)d_in[7], (const float*)d_in[9]};
  const float* b[4] = {(const float*)d_in[4], (const float*)d_in[6],
                       (const float*)d_in[8], (const float*)d_in[10]};
  const float* Wo = (const float*)d_in[11];
  const float* bo = (const float*)d_in[12];
  float* out = (float*)d_out;

  const int Bsz = in_sizes[0] / 256;  // 32768

  _Float16* hb = (_Float16*)d_ws;
  _Float16* WiP = hb;                   // 65536
  _Float16* WoP = hb + 65536;           // 4096
  _Float16* PQP = hb + 69632;           // 524288
  _Float16* RmP = hb + 593920;          // 196608
  _Float16* Wh  = hb + 790528;          // 262144
  _Float16* Wt  = hb + 1052672;         // 262144
  _Float16* Eh  = hb + 1314816;         // 262144
  _Float16* Th  = hb + 1576960;         // 262144
  _Float16* Ph  = hb + 1839104;         // 262144
  float* crm = (float*)(hb + 2101248);  // 768 floats

  k_pack<<<1296, 256, 0, stream>>>(W[0], W[1], W[2], W[3], Wi, Wo,
                                   Wh, Wt, RmP, WiP, WoP);
  k_crm<<<3, 256, 0, stream>>>(W[0], W[1], W[2], b[1], b[2], b[3], crm);
  const dim3 g64(4, 4, 4);
  k_smm<<<g64, 256, 0, stream>>>(Wh, Wh, Eh, 0.01f);  // E = DT^2 W W^T
  k_smm<<<g64, 256, 0, stream>>>(Eh, Eh, Th, 1.0f);   // T = E^2
  k_pP<<<g64, 256, 0, stream>>>(Eh, Th, Ph, PQP);     // P, pack -P
  k_pQ<<<g64, 256, 0, stream>>>(Wt, Ph, PQP);         // pack Q = 0.1 W^T P

  k_fused<<<Bsz / 64, 256, 0, stream>>>(x, WiP, PQP, RmP, WoP, bi,
                                        b[0], b[1], b[2], b[3], crm, bo, out);
}

// Round 5
// 222.701 us; speedup vs baseline: 4.5196x; 1.0556x over previous
//
#include <hip/hip_runtime.h>
#include <math.h>

#define DTC 0.1f

typedef _Float16 half8 __attribute__((ext_vector_type(8)));
typedef _Float16 half4v __attribute__((ext_vector_type(4)));
typedef float f32x4 __attribute__((ext_vector_type(4)));

__device__ __forceinline__ float fast_tanh(float x) {
  const float e = __expf(2.f * x);
  const float r = __builtin_amdgcn_rcpf(e + 1.f);
  return fmaf(-2.f, r, 1.f);
}

// ================= precompute =================================================

// Wh = fp16(W) ; Wt = fp16(W^T) ; crm[l][j] = -0.09 * sum_k b_{l+2}[k] W_l[k][j]
__global__ __launch_bounds__(256) void k_prep(
    const float* __restrict__ W0, const float* __restrict__ W1,
    const float* __restrict__ W2, const float* __restrict__ W3,
    const float* __restrict__ b2, const float* __restrict__ b3,
    const float* __restrict__ b4,
    _Float16* __restrict__ Wh, _Float16* __restrict__ Wt,
    float* __restrict__ crm) {
  const float* Ws[4] = {W0, W1, W2, W3};
  const int bid = blockIdx.x, tid = threadIdx.x;
  if (bid < 128) {
    const int t = bid * 256 + tid;
    const float* W = Ws[(t * 8) >> 16];
    const int off = (t * 8) & 65535;
    const float4 a = *(const float4*)&W[off];
    const float4 b = *(const float4*)&W[off + 4];
    half8 h;
    h[0] = (_Float16)a.x; h[1] = (_Float16)a.y; h[2] = (_Float16)a.z; h[3] = (_Float16)a.w;
    h[4] = (_Float16)b.x; h[5] = (_Float16)b.y; h[6] = (_Float16)b.z; h[7] = (_Float16)b.w;
    *(half8*)&Wh[t * 8] = h;
  } else if (bid < 384) {
    __shared__ float sh[32][33];
    const int b2i = bid - 128;
    const int l = b2i >> 6, t64 = b2i & 63;
    const int r0 = (t64 >> 3) * 32, c0 = (t64 & 7) * 32;
    const float* W = Ws[l];
    const int i = tid >> 5, j = tid & 31;
#pragma unroll
    for (int p = 0; p < 4; ++p)
      sh[p * 8 + i][j] = W[(r0 + p * 8 + i) * 256 + c0 + j];
    __syncthreads();
#pragma unroll
    for (int p = 0; p < 4; ++p)
      Wt[l * 65536 + (c0 + p * 8 + i) * 256 + r0 + j] = (_Float16)sh[j][p * 8 + i];
  } else {
    const int l = bid - 384;
    const float* W = Ws[l];
    const float* b = (l == 0) ? b2 : (l == 1) ? b3 : b4;
    float s = 0.f;
#pragma unroll 8
    for (int k = 0; k < 256; ++k) s = fmaf(b[k], W[k * 256 + tid], s);
    crm[l * 256 + tid] = -0.09f * s;
  }
}

// C = scale*(A@B^T) [+ I - Eadd]   per layer (blockIdx.z), 256x256, fp16 rm out
__global__ __launch_bounds__(256) void k_smm3(const _Float16* __restrict__ A,
                                              const _Float16* __restrict__ B,
                                              const _Float16* __restrict__ Eadd,
                                              _Float16* __restrict__ C,
                                              float scale, int addI) {
  const int tid = threadIdx.x, wave = tid >> 6, lane = tid & 63;
  const int quad = lane >> 4, l16 = lane & 15;
  const int l = blockIdx.z;
  const _Float16* Al = A + (size_t)l * 65536;
  const _Float16* Bl = B + (size_t)l * 65536;
  _Float16* Cl = C + (size_t)l * 65536;
  const int m0 = blockIdx.y * 64 + wave * 16, n0 = blockIdx.x * 64;
  f32x4 acc[4] = {};
#pragma unroll
  for (int kt = 0; kt < 8; ++kt) {
    const half8 af = *(const half8*)&Al[(m0 + l16) * 256 + kt * 32 + quad * 8];
#pragma unroll
    for (int ni = 0; ni < 4; ++ni) {
      const half8 bf = *(const half8*)&Bl[(n0 + ni * 16 + l16) * 256 + kt * 32 + quad * 8];
      acc[ni] = __builtin_amdgcn_mfma_f32_16x16x32_f16(af, bf, acc[ni], 0, 0, 0);
    }
  }
#pragma unroll
  for (int ni = 0; ni < 4; ++ni)
#pragma unroll
    for (int r = 0; r < 4; ++r) {
      const int row = m0 + quad * 4 + r, col = n0 + ni * 16 + l16;
      float v = scale * acc[ni][r];
      if (addI) v += (row == col ? 1.f : 0.f) - (float)(Eadd + (size_t)l * 65536)[row * 256 + col];
      Cl[row * 256 + col] = (_Float16)v;
    }
}

// Destination-mapped coalesced packing of all B-frag weight buffers.
// chunk = 16B of 8 halves; packed idx = ((ntile*NKT+kt)*64 + lane)*8 + j
// holds B[n=ntile*16+(lane&15)][k=kt*32+(lane>>4)*8+j]
__global__ __launch_bounds__(256) void k_pack(
    const _Float16* __restrict__ Ph, const _Float16* __restrict__ Qt,
    const _Float16* __restrict__ Wt, const float* __restrict__ Wi,
    const float* __restrict__ Wo,
    _Float16* __restrict__ PQP, _Float16* __restrict__ RmP,
    _Float16* __restrict__ WiP, _Float16* __restrict__ WoP) {
  const int t = blockIdx.x * 256 + threadIdx.x;
  if (t < 65536) {  // PQP: NKT=16, kt<8 -> -P (sym), kt>=8 -> Qt
    const int l = t >> 14, c = t & 16383;
    const int ntile = c >> 10, kt = (c >> 6) & 15, lb = c & 63;
    const int n = ntile * 16 + (lb & 15);
    const int kq = (lb >> 4) * 8;
    half8 h;
    if (kt < 8) {
      h = *(const half8*)&Ph[(size_t)l * 65536 + n * 256 + kt * 32 + kq];
#pragma unroll
      for (int j = 0; j < 8; ++j) h[j] = -h[j];
    } else {
      h = *(const half8*)&Qt[(size_t)l * 65536 + n * 256 + (kt - 8) * 32 + kq];
    }
    *(half8*)&PQP[(size_t)t * 8] = h;
  } else if (t < 90112) {  // RmP: NKT=8, B[n][k] = -0.9*Wt[n][k]
    const int tt = t - 65536;
    const int l = tt >> 13, c = tt & 8191;
    const int ntile = c >> 9, kt = (c >> 6) & 7, lb = c & 63;
    const int n = ntile * 16 + (lb & 15);
    const int k0 = kt * 32 + (lb >> 4) * 8;
    half8 h = *(const half8*)&Wt[(size_t)l * 65536 + n * 256 + k0];
#pragma unroll
    for (int j = 0; j < 8; ++j) h[j] = (_Float16)(-0.9f * (float)h[j]);
    *(half8*)&RmP[(size_t)tt * 8] = h;
  } else if (t < 98304) {  // WiP: NKT=8, B[n][k] = Wi[n][k]
    const int c = t - 90112;
    const int ntile = c >> 9, kt = (c >> 6) & 7, lb = c & 63;
    const int n = ntile * 16 + (lb & 15);
    const int k0 = kt * 32 + (lb >> 4) * 8;
    const float4 a = *(const float4*)&Wi[n * 256 + k0];
    const float4 b = *(const float4*)&Wi[n * 256 + k0 + 4];
    half8 h;
    h[0] = (_Float16)a.x; h[1] = (_Float16)a.y; h[2] = (_Float16)a.z; h[3] = (_Float16)a.w;
    h[4] = (_Float16)b.x; h[5] = (_Float16)b.y; h[6] = (_Float16)b.z; h[7] = (_Float16)b.w;
    *(half8*)&WiP[(size_t)c * 8] = h;
  } else {  // WoP: NKT=8, classes padded to 16
    const int c = t - 98304;  // 0..511
    const int kt = c >> 6, lb = c & 63;
    const int n = lb & 15;
    const int k0 = kt * 32 + (lb >> 4) * 8;
    half8 h;
#pragma unroll
    for (int j = 0; j < 8; ++j) h[j] = (_Float16)((n < 10) ? Wo[n * 256 + k0 + j] : 0.f);
    *(half8*)&WoP[(size_t)c * 8] = h;
  }
}

// ================= fused persistent batch kernel =============================

__device__ __forceinline__ void lds_w16h(_Float16* base, int row, int col, _Float16 v) {
  const int chunk = (col >> 3) ^ (row & 7);
  *(_Float16*)((char*)base + row * 512 + (chunk << 4) + (col & 7) * 2) = v;
}

// wave tile 64 rows x 32 cols (ni=2); B-frags ring-prefetched from global (L2)
template <int NKT, bool DUAL>
__device__ __forceinline__ void gemm_k(const _Float16* __restrict__ Bp,
                                       const _Float16* A1, const _Float16* A2,
                                       f32x4* acc, int wave, int lane, int quad, int l16) {
  half8 bf[3][2];
  auto loadB = [&](int kt, int s) {
#pragma unroll
    for (int ni = 0; ni < 2; ++ni)
      bf[s][ni] = *(const half8*)&Bp[(((wave * 2 + ni) * NKT + kt) * 64 + lane) * 8];
  };
  loadB(0, 0);
  loadB(1, 1);
#pragma unroll
  for (int kt = 0; kt < NKT; ++kt) {
    const int s = kt % 3;
    if (kt + 2 < NKT) loadB(kt + 2, (kt + 2) % 3);
    const _Float16* Ab = (DUAL && kt >= NKT / 2) ? A2 : A1;
    const int akt = DUAL ? (kt & (NKT / 2 - 1)) : kt;
    half8 af[4];
#pragma unroll
    for (int mi = 0; mi < 4; ++mi) {
      const int row = mi * 16 + l16;
      const int chunk = (akt * 4 + quad) ^ (row & 7);
      af[mi] = *(const half8*)((const char*)Ab + row * 512 + (chunk << 4));
    }
#pragma unroll
    for (int mi = 0; mi < 4; ++mi)
#pragma unroll
      for (int ni = 0; ni < 2; ++ni)
        acc[mi * 2 + ni] = __builtin_amdgcn_mfma_f32_16x16x32_f16(
            af[mi], bf[s][ni], acc[mi * 2 + ni], 0, 0, 0);
  }
}

__global__ __launch_bounds__(512, 4) void k_fused(
    const float* __restrict__ x, const _Float16* __restrict__ WiP,
    const _Float16* __restrict__ PQP, const _Float16* __restrict__ RmP,
    const _Float16* __restrict__ WoP, const float* __restrict__ bi,
    const float* __restrict__ b1, const float* __restrict__ b2,
    const float* __restrict__ b3, const float* __restrict__ b4,
    const float* __restrict__ crm, const float* __restrict__ bo,
    float* __restrict__ out) {
  __shared__ __align__(16) _Float16 A1[64 * 256];
  __shared__ __align__(16) _Float16 A2[64 * 256];
  const int tid = threadIdx.x;
  const int wave = tid >> 6, lane = tid & 63;
  const int quad = lane >> 4, l16 = lane & 15;
  const int m0 = blockIdx.x * 64;

  // ---- stage x: fp32 HBM -> fp16 swizzled LDS (A1) ----
#pragma unroll
  for (int it = 0; it < 8; ++it) {
    const int idx = it * 512 + tid;
    const int row = idx >> 6, c4 = idx & 63;
    const float4 v = *(const float4*)&x[(size_t)(m0 + row) * 256 + c4 * 4];
    const int chunk = (c4 >> 1) ^ (row & 7), part = c4 & 1;
    _Float16* p = (_Float16*)((char*)A1 + row * 512 + (chunk << 4) + (part << 3));
    p[0] = (_Float16)v.x; p[1] = (_Float16)v.y; p[2] = (_Float16)v.z; p[3] = (_Float16)v.w;
  }
  __syncthreads();

  f32x4 acc[8];
  const f32x4 zero = {0.f, 0.f, 0.f, 0.f};
  half4v uph[8], r2p[8];

  // ---- GEMM0: z = x@WiT ; A1 = r1 = z+bi+0.1*b1 ; A2 = regs = r2 = tanh(z+bi)
#pragma unroll
  for (int t = 0; t < 8; ++t) acc[t] = zero;
  gemm_k<8, false>(WiP, A1, A1, acc, wave, lane, quad, l16);
  __syncthreads();
#pragma unroll
  for (int ni = 0; ni < 2; ++ni) {
    const int col = wave * 32 + ni * 16 + l16;
    const float bic = bi[col], b1c = DTC * b1[col];
#pragma unroll
    for (int mi = 0; mi < 4; ++mi) {
      half4v r2v;
#pragma unroll
      for (int r = 0; r < 4; ++r) {
        const float z = acc[mi * 2 + ni][r] + bic;
        const int row = mi * 16 + quad * 4 + r;
        lds_w16h(A1, row, col, (_Float16)(z + b1c));
        r2v[r] = (_Float16)fast_tanh(z);
        lds_w16h(A2, row, col, r2v[r]);
      }
      r2p[mi * 2 + ni] = r2v;
    }
  }
  __syncthreads();

  // ---- 4 transport layers ----
#pragma unroll 1
  for (int l = 0; l < 4; ++l) {
    // u' = r1@Pm + r2@Q   (K=512)
#pragma unroll
    for (int t = 0; t < 8; ++t) acc[t] = zero;
    gemm_k<16, true>(PQP + (size_t)l * 131072, A1, A2, acc, wave, lane, quad, l16);
    __syncthreads();
    const float* bn = (l == 0) ? b2 : (l == 1) ? b3 : b4;
#pragma unroll
    for (int ni = 0; ni < 2; ++ni) {
      const int col = wave * 32 + ni * 16 + l16;
      const float bc = (l < 3) ? DTC * bn[col] : 0.f;
#pragma unroll
      for (int mi = 0; mi < 4; ++mi) {
        half4v uv;
#pragma unroll
        for (int r = 0; r < 4; ++r) {
          uv[r] = (_Float16)acc[mi * 2 + ni][r];
          lds_w16h(A1, mi * 16 + quad * 4 + r, col, (_Float16)(acc[mi * 2 + ni][r] + bc));
        }
        uph[mi * 2 + ni] = uv;
      }
    }
    __syncthreads();
    if (l < 3) {
      // v' = r1@Rm - crm - r2 ; new r2 = (v' + 10 tanh u')/11
#pragma unroll
      for (int t = 0; t < 8; ++t) acc[t] = zero;
      gemm_k<8, false>(RmP + (size_t)l * 65536, A1, A1, acc, wave, lane, quad, l16);
#pragma unroll
      for (int ni = 0; ni < 2; ++ni) {
        const int col = wave * 32 + ni * 16 + l16;
        const float cc = crm[l * 256 + col];
#pragma unroll
        for (int mi = 0; mi < 4; ++mi) {
          half4v nr2;
#pragma unroll
          for (int r = 0; r < 4; ++r) {
            const float vp = acc[mi * 2 + ni][r] - cc - (float)r2p[mi * 2 + ni][r];
            nr2[r] = (_Float16)((vp + 10.f * fast_tanh((float)uph[mi * 2 + ni][r])) * (1.f / 11.f));
            lds_w16h(A2, mi * 16 + quad * 4 + r, col, nr2[r]);
          }
          r2p[mi * 2 + ni] = nr2;
        }
      }
      __syncthreads();
    }
  }

  // ---- head: logits = z@Wo^T + bo (MFMA, 16-padded classes); softmax ----
  if (wave < 4) {
    f32x4 acch = zero;
#pragma unroll
    for (int kt = 0; kt < 8; ++kt) {
      const int row = wave * 16 + l16;
      const int chunk = (kt * 4 + quad) ^ (row & 7);
      const half8 af = *(const half8*)((const char*)A1 + row * 512 + (chunk << 4));
      const half8 bfr = *(const half8*)&WoP[(kt * 64 + lane) * 8];
      acch = __builtin_amdgcn_mfma_f32_16x16x32_f16(af, bfr, acch, 0, 0, 0);
    }
    const float bov = (l16 < 10) ? bo[l16] : -3.0e38f;
#pragma unroll
    for (int r = 0; r < 4; ++r) {
      float v = acch[r] + bov;
      float mx = v;
#pragma unroll
      for (int off = 1; off < 16; off <<= 1) mx = fmaxf(mx, __shfl_xor(mx, off, 64));
      const float e = __expf(v - mx);
      float s = e;
#pragma unroll
      for (int off = 1; off < 16; off <<= 1) s += __shfl_xor(s, off, 64);
      if (l16 < 10)
        out[(size_t)(m0 + wave * 16 + quad * 4 + r) * 10 + l16] = e * __builtin_amdgcn_rcpf(s);
    }
  }
}

// ================= launcher ==================================================

extern "C" void kernel_launch(void* const* d_in, const int* in_sizes, int n_in,
                              void* d_out, int out_size, void* d_ws, size_t ws_size,
                              hipStream_t stream) {
  const float* x  = (const float*)d_in[0];
  const float* Wi = (const float*)d_in[1];
  const float* bi = (const float*)d_in[2];
  const float* W[4] = {(const float*)d_in[3], (const float*)d_in[5],
                       (const float*)d_in[7], (const float*)d_in[9]};
  const float* b[4] = {(const float*)d_in[4], (const float*)d_in[6],
                       (const float*)d_in[8], (const float*)d_in[10]};
  const float* Wo = (const float*)d_in[11];
  const float* bo = (const float*)d_in[12];
  float* out = (float*)d_out;

  const int Bsz = in_sizes[0] / 256;  // 32768

  _Float16* hb = (_Float16*)d_ws;
  _Float16* WiP = hb;                   // 65536
  _Float16* WoP = hb + 65536;           // 4096
  _Float16* PQP = hb + 69632;           // 524288
  _Float16* RmP = hb + 593920;          // 196608
  _Float16* Wh  = hb + 790528;          // 262144
  _Float16* Wt  = hb + 1052672;         // 262144
  _Float16* Eh  = hb + 1314816;         // 262144
  _Float16* Ph  = hb + 1576960;         // 262144
  _Float16* Qt  = hb + 1839104;         // 262144
  float* crm = (float*)(hb + 2101248);  // 768 floats

  const dim3 g64(4, 4, 4);
  k_prep<<<387, 256, 0, stream>>>(W[0], W[1], W[2], W[3], b[1], b[2], b[3],
                                  Wh, Wt, crm);
  k_smm3<<<g64, 256, 0, stream>>>(Wh, Wh, nullptr, Eh, 0.01f, 0);  // E = DT^2 W W^T
  k_smm3<<<g64, 256, 0, stream>>>(Eh, Eh, Eh, Ph, 1.0f, 1);        // P = I - E + E^2
  k_smm3<<<g64, 256, 0, stream>>>(Ph, Wt, nullptr, Qt, DTC, 0);    // Qt = 0.1 P@W
  k_pack<<<386, 256, 0, stream>>>(Ph, Qt, Wt, Wi, Wo, PQP, RmP, WiP, WoP);

  k_fused<<<Bsz / 64, 512, 0, stream>>>(x, WiP, PQP, RmP, WoP, bi,
                                        b[0], b[1], b[2], b[3], crm, bo, out);
}